// Round 7
// baseline (131.374 us; speedup 1.0000x reference)
//
#include <hip/hip_runtime.h>

#define CDIM 64
#define TDIM 24
#define NDIM 512
#define NBT  192   // B*T = 8*24

typedef float    float4v __attribute__((ext_vector_type(4)));
typedef _Float16 half8v  __attribute__((ext_vector_type(8)));
typedef _Float16 half4v  __attribute__((ext_vector_type(4)));
typedef _Float16 half2v  __attribute__((ext_vector_type(2)));

// ---------------------------------------------------------------------------
// Workspace layout (bytes):
//   VT_g : _Float16 [NBT][64][512]  0         (12582912)
//   F16  : _Float16 [NBT][2][512]   12582912  (393216)  exp2(d)
//   P16  : _Float16 [NBT][2][512]   12976128  (393216)  exp2(0.2 d)
//   E16  : _Float16 [NBT][2][512]   13369344  (393216)  exp2(s-6)
//   Q16  : _Float16 [NBT][2][512]   13762560  (393216)  exp2(0.2 s-6)
//   maskb: u8       [512][512]      14155776  (262144)  {0x00,0xFF}
// Budget: harness fills ~86-90 us/iter (256 MiB x2 re-poison, immovable),
// k1 ~1-2 us, k2 the only optimizable term. R4-R6 proved barrier-schedule
// variants are all ~30 us -> this round DELETES V-staging (VT is L2-hot,
// 64 KB/bt shared by 4 XCD-colocated blocks): zero main-loop barriers,
// direct global b0/b1 reads with immediate offsets.
// ---------------------------------------------------------------------------

__device__ __forceinline__ float exp2_fast(float x) {
#if __has_builtin(__builtin_amdgcn_exp2f)
  return __builtin_amdgcn_exp2f(x);
#else
  return __expf(x * 0.69314718f);
#endif
}

// ======== kernel 1: V = X @ Wv^T (f16 MFMA) + exp2 tables + mask pack ======
struct SmemK1 {
  union {
    _Float16 xt[128][72];    // X tile [node][c], 144 B rows
    _Float16 vtb[64][136];   // V^T bounce [c][node]
  } big;                     // 18432 B
  _Float16 wv[64][72];       // Wv [d][k]             9216 B
  _Float16 wext[16][72];     // rows 0..3 = log2e * (a_h^T W_h), rest 0   2304 B
};                            // 29952 B

__launch_bounds__(256, 4)
__global__ void k1_v(const float* __restrict__ x,  const float* __restrict__ Wv,
                     const float* __restrict__ Wq, const float* __restrict__ Wk,
                     const float* __restrict__ a_src, const float* __restrict__ a_dst,
                     const int* __restrict__ gso,
                     _Float16* __restrict__ VT_g,
                     _Float16* __restrict__ F16, _Float16* __restrict__ P16,
                     _Float16* __restrict__ E16, _Float16* __restrict__ Q16,
                     unsigned char* __restrict__ maskb) {
  const int t  = threadIdx.x;
  const int bx = blockIdx.x;

  if (bx >= 768) {   // ---- mask-pack blocks: 16 ints -> 16 mask bytes each ----
    int g = (bx - 768) * 256 + t;            // 0..16383
    const int4* gp = (const int4*)gso + (size_t)g * 4;
    unsigned w[4];
#pragma unroll
    for (int k = 0; k < 4; ++k) {
      int4 v = gp[k];
      w[k] = (v.x ? 0x000000FFu : 0u) | (v.y ? 0x0000FF00u : 0u) |
             (v.z ? 0x00FF0000u : 0u) | (v.w ? 0xFF000000u : 0u);
    }
    uint4 o; o.x = w[0]; o.y = w[1]; o.z = w[2]; o.w = w[3];
    ((uint4*)maskb)[g] = o;
    return;
  }

  __shared__ SmemK1 sm;
  const int qn = bx & 3;
  const int bt = bx >> 2;
  const int b  = bt / TDIM, tt = bt % TDIM;
  const int n0 = qn * 128;

  // stage Wv -> f16 LDS (dwordx4 loads)
#pragma unroll
  for (int it = 0; it < 4; ++it) {
    int idx = it * 256 + t;                 // 0..1023 float4s
    float4 vv = ((const float4*)Wv)[idx];
    int d = idx >> 4, k4 = (idx & 15) * 4;
    half4v h4; h4[0] = (_Float16)vv.x; h4[1] = (_Float16)vv.y;
    h4[2] = (_Float16)vv.z; h4[3] = (_Float16)vv.w;
    *(half4v*)&sm.wv[d][k4] = h4;
  }
  // wext: zero rows 4..15; rows 0..3 = log2e * (a_h^T W_h)  (exp2 domain)
  for (int z = t; z < 12 * 72; z += 256) ((_Float16*)sm.wext[4])[z] = (_Float16)0.f;
  if (t < 64) {
    int c = t;
    float s0 = 0.f, s1 = 0.f, d0 = 0.f, d1 = 0.f;
#pragma unroll
    for (int d = 0; d < 32; ++d) {
      s0 += a_src[d]      * Wq[d * 64 + c];
      s1 += a_src[32 + d] * Wq[(32 + d) * 64 + c];
      d0 += a_dst[d]      * Wk[d * 64 + c];
      d1 += a_dst[32 + d] * Wk[(32 + d) * 64 + c];
    }
    const float l2e = 1.44269504f;
    sm.wext[0][c] = (_Float16)(s0 * l2e); sm.wext[1][c] = (_Float16)(s1 * l2e);
    sm.wext[2][c] = (_Float16)(d0 * l2e); sm.wext[3][c] = (_Float16)(d1 * l2e);
  }
  // stage X tile (channel pairs -> half2)
  for (int it = 0; it < 16; ++it) {
    int idx = it * 256 + t;
    int cp = idx >> 7, n = idx & 127;
    int c0 = cp * 2;
    const float* base = x + ((size_t)(b * CDIM + c0) * TDIM + tt) * NDIM + n0 + n;
    half2v p; p[0] = (_Float16)base[0]; p[1] = (_Float16)base[(size_t)TDIM * NDIM];
    *(half2v*)&sm.big.xt[n][c0] = p;
  }
  __syncthreads();

  const int lane = t & 63, w = t >> 6;
  const int m = lane & 15, quad = lane >> 4;
  const int mbase = w * 32;   // 32 nodes per wave

  float4v acc[2][5];
#pragma unroll
  for (int mt = 0; mt < 2; ++mt)
#pragma unroll
    for (int nt = 0; nt < 5; ++nt)
#pragma unroll
      for (int r = 0; r < 4; ++r) acc[mt][nt][r] = 0.f;

#pragma unroll
  for (int ks = 0; ks < 2; ++ks) {
    half8v af[2], bf[5];
#pragma unroll
    for (int mt = 0; mt < 2; ++mt)
      af[mt] = *(const half8v*)&sm.big.xt[mbase + mt * 16 + m][ks * 32 + quad * 8];
#pragma unroll
    for (int nt = 0; nt < 4; ++nt)
      bf[nt] = *(const half8v*)&sm.wv[nt * 16 + m][ks * 32 + quad * 8];
    bf[4] = *(const half8v*)&sm.wext[m][ks * 32 + quad * 8];
#pragma unroll
    for (int mt = 0; mt < 2; ++mt)
#pragma unroll
      for (int nt = 0; nt < 5; ++nt)
        acc[mt][nt] = __builtin_amdgcn_mfma_f32_16x16x32_f16(af[mt], bf[nt], acc[mt][nt], 0, 0, 0);
  }

  // exp2 tables (col 0/1 = ssrc h0/h1 -> E/Q; col 2/3 = sdst h0/h1 -> F/P)
  if (m < 4) {
    const int hh = m & 1;
    const bool is_src = (m < 2);
    _Float16* eb = (is_src ? E16 : F16) + ((size_t)(bt * 2 + hh)) * NDIM;
    _Float16* qb = (is_src ? Q16 : P16) + ((size_t)(bt * 2 + hh)) * NDIM;
    const float bias = is_src ? -6.f : 0.f;
#pragma unroll
    for (int mt = 0; mt < 2; ++mt)
#pragma unroll
      for (int r = 0; r < 4; ++r) {
        float s = acc[mt][4][r];
        int n = n0 + mbase + mt * 16 + quad * 4 + r;
        eb[n] = (_Float16)exp2_fast(s + bias);
        qb[n] = (_Float16)exp2_fast(0.2f * s + bias);
      }
  }
  __syncthreads();   // xt fully consumed before overlay

  // V^T bounce into LDS (pack node pairs)
#pragma unroll
  for (int mt = 0; mt < 2; ++mt)
#pragma unroll
    for (int nt = 0; nt < 4; ++nt)
#pragma unroll
      for (int r = 0; r < 4; r += 2) {
        int nl = mbase + mt * 16 + quad * 4 + r;
        int c  = nt * 16 + m;
        half2v p = __builtin_bit_cast(half2v,
            __builtin_amdgcn_cvt_pkrtz(acc[mt][nt][r], acc[mt][nt][r + 1]));
        *(half2v*)&sm.big.vtb[c][nl] = p;
      }
  __syncthreads();

  // coalesced V^T -> global, dwordx4 (4 iters: 64 rows x 16 uint4)
  const uint4* vq = (const uint4*)sm.big.vtb;   // row stride 17 uint4 (272 B)
#pragma unroll
  for (int it = 0; it < 4; ++it) {
    int idx = it * 256 + t;                     // 0..1023
    int c = idx >> 4, q4 = idx & 15;
    ((uint4*)VT_g)[(size_t)(bt * 64 + c) * 64 + qn * 16 + q4] = vq[c * 17 + q4];
  }
}

// ======== kernel 2: masked softmax(P) @ V + LayerNorm + transpose ===========
// ROWBLK=128: 4 i-tiles x 192 bt = 768 blocks (3/CU). XCD swizzle keeps the
// 4 blocks sharing one 64 KB VT panel on one XCD's L2.
// ZERO-BARRIER main loop: V^T and masks are read DIRECTLY from global (L2-
// hot; total VT demand ~98 MB ≈ 3 us of L2 BW). Only LDS use is the small
// read-only F/P tables (staged once, one barrier) -> no commit phase, no
// vmcnt drains, no main-loop syncs; latency hidden by ILP (32 independent
// VT loads off 2 base pointers with compile-time immediate offsets) + TLP.
// e_ij = max(E_i*F_j, Q_i*P_j) in packed f16 (exp2 tables from k1).
struct SmemK2 {
  union {
    struct { _Float16 sF16[2][512]; _Float16 sP16[2][512]; } f;    // 4096
    struct { float otile[128][66]; float rsum[2][128]; float rsq[2][128];
             float mu[128]; float rs[128]; } e;                    // 36864
  } u;
};                          // 36864 B

__launch_bounds__(256, 3)
__global__ void k2_attn(const _Float16* __restrict__ VT_g,
                        const _Float16* __restrict__ F16, const _Float16* __restrict__ P16,
                        const _Float16* __restrict__ E16, const _Float16* __restrict__ Q16,
                        const unsigned char* __restrict__ maskb,
                        const float* __restrict__ gamma, const float* __restrict__ beta,
                        float* __restrict__ out) {
  __shared__ SmemK2 sm;
  const int t     = threadIdx.x;
  const int id    = blockIdx.x;
  const int itile = (id >> 3) & 3;
  const int bt    = ((id >> 5) << 3) | (id & 7);
  const int i0    = itile * 128;
  const int b     = bt / TDIM, tt = bt % TDIM;
  const int lane  = t & 63, w = t >> 6;
  const int h = w >> 1, ihalf = w & 1;
  const int m = lane & 15, quad = lane >> 4;
  const int rbase = ihalf * 64;    // this wave's 64-row half of the 128-row tile

  // stage F/P f16 tables -> LDS (one uint2 per thread each)
  {
    uint2 fv = ((const uint2*)(F16 + (size_t)bt * 2 * NDIM))[t];
    uint2 pw = ((const uint2*)(P16 + (size_t)bt * 2 * NDIM))[t];
    ((uint2*)sm.u.f.sF16)[t] = fv;
    ((uint2*)sm.u.f.sP16)[t] = pw;
  }
  // per-row source factors: direct f16 table loads -> packed half2 splats
  half2v e2[4], q2[4];
  {
    const _Float16* eb = E16 + ((size_t)(bt * 2 + h)) * NDIM + i0 + rbase + m;
    const _Float16* qb = Q16 + ((size_t)(bt * 2 + h)) * NDIM + i0 + rbase + m;
#pragma unroll
    for (int mt = 0; mt < 4; ++mt) {
      _Float16 ev = eb[mt * 16];
      _Float16 qv = qb[mt * 16];
      e2[mt][0] = ev; e2[mt][1] = ev;
      q2[mt][0] = qv; q2[mt][1] = qv;
    }
  }

  float4v acc[4][2], accs[4];
#pragma unroll
  for (int mt = 0; mt < 4; ++mt)
#pragma unroll
    for (int r = 0; r < 4; ++r) { acc[mt][0][r] = 0.f; acc[mt][1][r] = 0.f; accs[mt][r] = 0.f; }
  const half8v bones = {(_Float16)1.f, (_Float16)1.f, (_Float16)1.f, (_Float16)1.f,
                        (_Float16)1.f, (_Float16)1.f, (_Float16)1.f, (_Float16)1.f};

  // per-lane V^T row pointers (b0: row h*32+m, b1: +16); offsets are
  // compile-time immediates js*256+ksl*64 bytes (max 3968 < 4096 imm field)
  const _Float16* vr0 = VT_g + ((size_t)(bt * 64 + h * 32 + m)) * NDIM + quad * 8;
  const _Float16* vr1 = vr0 + (size_t)16 * NDIM;
  // per-lane mask row pointers (rows i0+rbase+mt*16+m; L2-hot 256 KB total)
  const unsigned char* mr0 = maskb + (size_t)(i0 + rbase + m) * NDIM + quad * 8;
  const unsigned char* mr1 = mr0 + (size_t)16 * NDIM;
  const unsigned char* mr2 = mr0 + (size_t)32 * NDIM;
  const unsigned char* mr3 = mr0 + (size_t)48 * NDIM;

  __syncthreads();   // F/P tables ready; ONLY barrier before the epilogue

#define SLICE(js_, ksl_)                                                       \
  {                                                                            \
    const int jq = (ksl_) * 32 + quad * 8;                                     \
    half8v F8 = *(const half8v*)&sm.u.f.sF16[h][(js_) * 128 + jq];             \
    half8v P8 = *(const half8v*)&sm.u.f.sP16[h][(js_) * 128 + jq];             \
    half8v b0 = *(const half8v*)(vr0 + (js_) * 128 + (ksl_) * 32);             \
    half8v b1 = *(const half8v*)(vr1 + (js_) * 128 + (ksl_) * 32);             \
    uint4 fu = __builtin_bit_cast(uint4, F8);                                  \
    uint4 pu = __builtin_bit_cast(uint4, P8);                                  \
    half2v f2a = __builtin_bit_cast(half2v, fu.x), f2b = __builtin_bit_cast(half2v, fu.y); \
    half2v f2c = __builtin_bit_cast(half2v, fu.z), f2d = __builtin_bit_cast(half2v, fu.w); \
    half2v p2a = __builtin_bit_cast(half2v, pu.x), p2b = __builtin_bit_cast(half2v, pu.y); \
    half2v p2c = __builtin_bit_cast(half2v, pu.z), p2d = __builtin_bit_cast(half2v, pu.w); \
    _Pragma("unroll")                                                          \
    for (int mt = 0; mt < 4; ++mt) {                                           \
      unsigned mw0 = mk[mt][ksl_].x, mw1 = mk[mt][ksl_].y;                     \
      uint4 eu;                                                                \
      eu.x = __builtin_bit_cast(unsigned,                                      \
               __builtin_elementwise_max(e2[mt] * f2a, q2[mt] * p2a)) &        \
             __builtin_amdgcn_perm(0u, mw0, 0x01010000u);                      \
      eu.y = __builtin_bit_cast(unsigned,                                      \
               __builtin_elementwise_max(e2[mt] * f2b, q2[mt] * p2b)) &        \
             __builtin_amdgcn_perm(0u, mw0, 0x03030202u);                      \
      eu.z = __builtin_bit_cast(unsigned,                                      \
               __builtin_elementwise_max(e2[mt] * f2c, q2[mt] * p2c)) &        \
             __builtin_amdgcn_perm(0u, mw1, 0x01010000u);                      \
      eu.w = __builtin_bit_cast(unsigned,                                      \
               __builtin_elementwise_max(e2[mt] * f2d, q2[mt] * p2d)) &        \
             __builtin_amdgcn_perm(0u, mw1, 0x03030202u);                      \
      half8v af = __builtin_bit_cast(half8v, eu);                              \
      acc[mt][0] = __builtin_amdgcn_mfma_f32_16x16x32_f16(af, b0,    acc[mt][0], 0, 0, 0); \
      acc[mt][1] = __builtin_amdgcn_mfma_f32_16x16x32_f16(af, b1,    acc[mt][1], 0, 0, 0); \
      accs[mt]   = __builtin_amdgcn_mfma_f32_16x16x32_f16(af, bones, accs[mt],   0, 0, 0); \
    }                                                                          \
  }

#pragma unroll
  for (int js = 0; js < 4; ++js) {
    // mask bytes for this quarter: 16 x uint2 per lane, immediate offsets
    uint2 mk[4][4];
#pragma unroll
    for (int ksl = 0; ksl < 4; ++ksl) {
      mk[0][ksl] = *(const uint2*)(mr0 + js * 128 + ksl * 32);
      mk[1][ksl] = *(const uint2*)(mr1 + js * 128 + ksl * 32);
      mk[2][ksl] = *(const uint2*)(mr2 + js * 128 + ksl * 32);
      mk[3][ksl] = *(const uint2*)(mr3 + js * 128 + ksl * 32);
    }
    SLICE(js, 0);
    SLICE(js, 1);
    SLICE(js, 2);
    SLICE(js, 3);
  }
#undef SLICE

  __syncthreads();   // F/P tables dead -> otile overlay
  // normalize by row sums (same C-layout row as acc -> no shuffle needed)
#pragma unroll
  for (int mt = 0; mt < 4; ++mt)
#pragma unroll
    for (int r = 0; r < 4; ++r) {
      float sc = __builtin_amdgcn_rcpf(accs[mt][r]);
      int i_loc = rbase + mt * 16 + quad * 4 + r;
#pragma unroll
      for (int nt = 0; nt < 2; ++nt)
        sm.u.e.otile[i_loc][h * 32 + nt * 16 + m] = acc[mt][nt][r] * sc;
    }
  __syncthreads();

  // LayerNorm over C=64 per row (128 rows, 2 threads/row x 32 ch)
  {
    int i = t & 127, cg = t >> 7;
    float s1 = 0.f, s2 = 0.f;
#pragma unroll
    for (int cc = 0; cc < 32; ++cc) {
      float v = sm.u.e.otile[i][cg * 32 + cc];
      s1 += v; s2 += v * v;
    }
    sm.u.e.rsum[cg][i] = s1;
    sm.u.e.rsq[cg][i]  = s2;
  }
  __syncthreads();
  if (t < 128) {
    int i = t;
    float s1 = sm.u.e.rsum[0][i] + sm.u.e.rsum[1][i];
    float s2 = sm.u.e.rsq[0][i]  + sm.u.e.rsq[1][i];
    float mu  = s1 * (1.f / 64.f);
    float var = s2 * (1.f / 64.f) - mu * mu;
    sm.u.e.mu[i] = mu;
    sm.u.e.rs[i] = rsqrtf(var + 1e-5f);
  }
  __syncthreads();
  {
    int i = t & 127, cg = t >> 7;
    float mu = sm.u.e.mu[i], rs = sm.u.e.rs[i];
    int n = i0 + i;
#pragma unroll
    for (int cc = 0; cc < 32; ++cc) {
      int c = cg * 32 + cc;
      float v = (sm.u.e.otile[i][c] - mu) * rs * gamma[c] + beta[c];
      out[((size_t)(b * CDIM + c) * TDIM + tt) * NDIM + n] = v;
    }
  }
}

// ---------------------------------------------------------------------------
extern "C" void kernel_launch(void* const* d_in, const int* in_sizes, int n_in,
                              void* d_out, int out_size, void* d_ws, size_t ws_size,
                              hipStream_t stream) {
  const float* x     = (const float*)d_in[0];
  const int*   gso   = (const int*)d_in[1];
  const float* Wq    = (const float*)d_in[2];
  const float* Wk    = (const float*)d_in[3];
  const float* Wv    = (const float*)d_in[4];
  const float* a_src = (const float*)d_in[5];
  const float* a_dst = (const float*)d_in[6];
  const float* gamma = (const float*)d_in[7];
  const float* beta  = (const float*)d_in[8];
  float* out = (float*)d_out;

  char* ws = (char*)d_ws;
  _Float16* VT_g = (_Float16*)ws;
  _Float16* F16  = (_Float16*)(ws + 12582912);
  _Float16* P16  = (_Float16*)(ws + 12976128);
  _Float16* E16  = (_Float16*)(ws + 13369344);
  _Float16* Q16  = (_Float16*)(ws + 13762560);
  unsigned char* maskb = (unsigned char*)(ws + 14155776);

  k1_v<<<832, 256, 0, stream>>>(x, Wv, Wq, Wk, a_src, a_dst, gso,
                                VT_g, F16, P16, E16, Q16, maskb);
  k2_attn<<<768, 256, 0, stream>>>(VT_g, F16, P16, E16, Q16, maskb,
                                   gamma, beta, out);
}

// Round 8
// 126.622 us; speedup vs baseline: 1.0375x; 1.0375x over previous
//
#include <hip/hip_runtime.h>

#define CDIM 64
#define TDIM 24
#define NDIM 512
#define NBT  192   // B*T = 8*24

typedef float    float4v __attribute__((ext_vector_type(4)));
typedef _Float16 half8v  __attribute__((ext_vector_type(8)));
typedef _Float16 half4v  __attribute__((ext_vector_type(4)));
typedef _Float16 half2v  __attribute__((ext_vector_type(2)));

// ---------------------------------------------------------------------------
// Workspace layout (bytes):
//   VT_g   : _Float16 [NBT][64][512]   0          (12582912 B)
//   s_src  : float    [NBT][2][512]    12582912   (786432 B)   (exp2 domain)
//   s_dst  : float    [NBT][2][512]    13369344   (786432 B)   (exp2 domain)
//   maskb  : u8       [512][512]       14155776   (262144 B)   {0x00,0xFF}
// Session budget: harness re-poison fills ~88-90 us/iter (2 x 256 MiB,
// immovable), k1 ~1.5 us, k2 ~28 us. Cross-round search: 128-row tile +
// LDS-staged VT + direct-global masks + 2-barrier-per-quarter = measured
// best (121.9); fewer barriers / no LDS staging both regress. This round:
// exact revert to that + double-buffered mask prefetch (the one exposed
// L2 round-trip left in the schedule).
// ---------------------------------------------------------------------------

__device__ __forceinline__ float exp2_fast(float x) {
#if __has_builtin(__builtin_amdgcn_exp2f)
  return __builtin_amdgcn_exp2f(x);
#else
  return __expf(x * 0.69314718f);
#endif
}

// ======== kernel 1: V = X @ Wv^T (f16 MFMA) + score cols + mask pack ========
// 1D grid, 832 blocks:
//   blocks 0..767  : compute; qn = bx & 3 (node quarter), bt = bx >> 2
//   blocks 768..831: gso -> byte-mask pack (pure BW, overlaps compute blocks)
struct SmemK1 {
  union {
    _Float16 xt[128][72];    // X tile [node][c], 144 B rows
    _Float16 vtb[64][136];   // V^T bounce [c][node]
  } big;                     // 18432 B
  _Float16 wv[64][72];       // Wv [d][k]             9216 B
  _Float16 wext[16][72];     // rows 0..3 = log2e * (a_h^T W_h), rest 0   2304 B
};                            // 29952 B

__launch_bounds__(256, 4)
__global__ void k1_v(const float* __restrict__ x,  const float* __restrict__ Wv,
                     const float* __restrict__ Wq, const float* __restrict__ Wk,
                     const float* __restrict__ a_src, const float* __restrict__ a_dst,
                     const int* __restrict__ gso,
                     _Float16* __restrict__ VT_g,
                     float* __restrict__ s_src_g, float* __restrict__ s_dst_g,
                     unsigned char* __restrict__ maskb) {
  const int t  = threadIdx.x;
  const int bx = blockIdx.x;

  if (bx >= 768) {   // ---- mask-pack blocks: 16 ints -> 16 mask bytes each ----
    int g = (bx - 768) * 256 + t;            // 0..16383
    const int4* gp = (const int4*)gso + (size_t)g * 4;
    unsigned w[4];
#pragma unroll
    for (int k = 0; k < 4; ++k) {
      int4 v = gp[k];
      w[k] = (v.x ? 0x000000FFu : 0u) | (v.y ? 0x0000FF00u : 0u) |
             (v.z ? 0x00FF0000u : 0u) | (v.w ? 0xFF000000u : 0u);
    }
    uint4 o; o.x = w[0]; o.y = w[1]; o.z = w[2]; o.w = w[3];
    ((uint4*)maskb)[g] = o;
    return;
  }

  __shared__ SmemK1 sm;
  const int qn = bx & 3;
  const int bt = bx >> 2;
  const int b  = bt / TDIM, tt = bt % TDIM;
  const int n0 = qn * 128;

  // stage Wv -> f16 LDS (dwordx4 loads)
#pragma unroll
  for (int it = 0; it < 4; ++it) {
    int idx = it * 256 + t;                 // 0..1023 float4s
    float4 vv = ((const float4*)Wv)[idx];
    int d = idx >> 4, k4 = (idx & 15) * 4;
    half4v h4; h4[0] = (_Float16)vv.x; h4[1] = (_Float16)vv.y;
    h4[2] = (_Float16)vv.z; h4[3] = (_Float16)vv.w;
    *(half4v*)&sm.wv[d][k4] = h4;
  }
  // wext: zero rows 4..15; rows 0..3 = log2e * (a_h^T W_h)  (exp2 domain)
  for (int z = t; z < 12 * 72; z += 256) ((_Float16*)sm.wext[4])[z] = (_Float16)0.f;
  if (t < 64) {
    int c = t;
    float s0 = 0.f, s1 = 0.f, d0 = 0.f, d1 = 0.f;
#pragma unroll
    for (int d = 0; d < 32; ++d) {
      s0 += a_src[d]      * Wq[d * 64 + c];
      s1 += a_src[32 + d] * Wq[(32 + d) * 64 + c];
      d0 += a_dst[d]      * Wk[d * 64 + c];
      d1 += a_dst[32 + d] * Wk[(32 + d) * 64 + c];
    }
    const float l2e = 1.44269504f;
    sm.wext[0][c] = (_Float16)(s0 * l2e); sm.wext[1][c] = (_Float16)(s1 * l2e);
    sm.wext[2][c] = (_Float16)(d0 * l2e); sm.wext[3][c] = (_Float16)(d1 * l2e);
  }
  // stage X tile (channel pairs -> half2)
  for (int it = 0; it < 16; ++it) {
    int idx = it * 256 + t;
    int cp = idx >> 7, n = idx & 127;
    int c0 = cp * 2;
    const float* base = x + ((size_t)(b * CDIM + c0) * TDIM + tt) * NDIM + n0 + n;
    half2v p; p[0] = (_Float16)base[0]; p[1] = (_Float16)base[(size_t)TDIM * NDIM];
    *(half2v*)&sm.big.xt[n][c0] = p;
  }
  __syncthreads();

  const int lane = t & 63, w = t >> 6;
  const int m = lane & 15, quad = lane >> 4;
  const int mbase = w * 32;   // 32 nodes per wave

  float4v acc[2][5];
#pragma unroll
  for (int mt = 0; mt < 2; ++mt)
#pragma unroll
    for (int nt = 0; nt < 5; ++nt)
#pragma unroll
      for (int r = 0; r < 4; ++r) acc[mt][nt][r] = 0.f;

#pragma unroll
  for (int ks = 0; ks < 2; ++ks) {
    half8v af[2], bf[5];
#pragma unroll
    for (int mt = 0; mt < 2; ++mt)
      af[mt] = *(const half8v*)&sm.big.xt[mbase + mt * 16 + m][ks * 32 + quad * 8];
#pragma unroll
    for (int nt = 0; nt < 4; ++nt)
      bf[nt] = *(const half8v*)&sm.wv[nt * 16 + m][ks * 32 + quad * 8];
    bf[4] = *(const half8v*)&sm.wext[m][ks * 32 + quad * 8];
#pragma unroll
    for (int mt = 0; mt < 2; ++mt)
#pragma unroll
      for (int nt = 0; nt < 5; ++nt)
        acc[mt][nt] = __builtin_amdgcn_mfma_f32_16x16x32_f16(af[mt], bf[nt], acc[mt][nt], 0, 0, 0);
  }

  // scatter score columns (col 0/1 = ssrc h0/h1, col 2/3 = sdst h0/h1)
  if (m < 4) {
    float* basep = (m < 2 ? s_src_g : s_dst_g) + (size_t)(bt * 2 + (m & 1)) * NDIM;
#pragma unroll
    for (int mt = 0; mt < 2; ++mt)
#pragma unroll
      for (int r = 0; r < 4; ++r)
        basep[n0 + mbase + mt * 16 + quad * 4 + r] = acc[mt][4][r];
  }
  __syncthreads();   // xt fully consumed before overlay

  // V^T bounce into LDS (pack node pairs)
#pragma unroll
  for (int mt = 0; mt < 2; ++mt)
#pragma unroll
    for (int nt = 0; nt < 4; ++nt)
#pragma unroll
      for (int r = 0; r < 4; r += 2) {
        int nl = mbase + mt * 16 + quad * 4 + r;
        int c  = nt * 16 + m;
        half2v p = __builtin_bit_cast(half2v,
            __builtin_amdgcn_cvt_pkrtz(acc[mt][nt][r], acc[mt][nt][r + 1]));
        *(half2v*)&sm.big.vtb[c][nl] = p;
      }
  __syncthreads();

  // coalesced V^T -> global, dwordx4 (4 iters: 64 rows x 16 uint4)
  const uint4* vq = (const uint4*)sm.big.vtb;   // row stride 17 uint4 (272 B)
#pragma unroll
  for (int it = 0; it < 4; ++it) {
    int idx = it * 256 + t;                     // 0..1023
    int c = idx >> 4, q4 = idx & 15;
    ((uint4*)VT_g)[(size_t)(bt * 64 + c) * 64 + qn * 16 + q4] = vq[c * 17 + q4];
  }
}

// ======== kernel 2: masked softmax(P) @ V + LayerNorm + transpose ===========
// ROWBLK=128: 4 i-tiles x 192 bt = 768 blocks (3/CU). XCD swizzle keeps the
// 4 blocks sharing one 64 KB VT panel on one XCD's L2:
//   id = (bt&7) + 8*itile + 32*(bt>>3)
// e_ij = max(E_i*F_j, Q_i*P_j), packed-f16 half2 ops. Masks direct from
// global (L2-hot), VT staged through LDS (2 barriers/quarter — measured best
// schedule). NEW: mask registers double-buffered (mkA/mkB, static via full
// js unroll): js=0 masks issue in the prologue; js+1 masks issue between
// SLICE 1 and 2, covered by 2 slices + commit + barrier (removes the one
// naked L2 round-trip per quarter).
struct SmemK2 {
  union {
    struct { _Float16 vt[64][128]; } s;                              // 16384
    struct { float otile[128][66]; float rsum[2][128]; float rsq[2][128];
             float mu[128]; float rs[128]; } e;                      // 36864
  } u;
  _Float16 sF16[2][512];   // 2048  F_j  = 2^{d'_j}   (f16)
  _Float16 sP16[2][512];   // 2048  Fp_j = 2^{0.2 d'_j} (f16)
};                          // 40960 B

__launch_bounds__(256, 3)
__global__ void k2_attn(const _Float16* __restrict__ VT_g,
                        const float* __restrict__ s_src_g, const float* __restrict__ s_dst_g,
                        const unsigned char* __restrict__ maskb,
                        const float* __restrict__ gamma, const float* __restrict__ beta,
                        float* __restrict__ out) {
  __shared__ SmemK2 sm;
  const int t     = threadIdx.x;
  const int id    = blockIdx.x;
  const int itile = (id >> 3) & 3;
  const int bt    = ((id >> 5) << 3) | (id & 7);
  const int i0    = itile * 128;
  const int b     = bt / TDIM, tt = bt % TDIM;
  const int lane  = t & 63, w = t >> 6;
  const int h = w >> 1, ihalf = w & 1;
  const int m = lane & 15, quad = lane >> 4;
  const int rbase = ihalf * 64;    // this wave's 64-row half of the 128-row tile

  // stage F/Fp as f16 (1024 exp2 pairs per block)
  for (int it = 0; it < 4; ++it) {
    int idx = it * 256 + t;
    float d = s_dst_g[(size_t)bt * 2 * NDIM + idx];
    ((_Float16*)sm.sF16)[idx] = (_Float16)exp2_fast(d);
    ((_Float16*)sm.sP16)[idx] = (_Float16)exp2_fast(0.2f * d);
  }
  // per-row source factors as packed half2 (bias -6 keeps products f16-normal)
  half2v e2[4], q2[4];
#pragma unroll
  for (int mt = 0; mt < 4; ++mt) {
    float sv = s_src_g[(size_t)(bt * 2 + h) * NDIM + i0 + rbase + mt * 16 + m];
    _Float16 ev = (_Float16)exp2_fast(sv - 6.f);
    _Float16 qv = (_Float16)exp2_fast(0.2f * sv - 6.f);
    e2[mt][0] = ev; e2[mt][1] = ev;
    q2[mt][0] = qv; q2[mt][1] = qv;
  }

  float4v acc[4][2], accs[4];
#pragma unroll
  for (int mt = 0; mt < 4; ++mt)
#pragma unroll
    for (int r = 0; r < 4; ++r) { acc[mt][0][r] = 0.f; acc[mt][1][r] = 0.f; accs[mt][r] = 0.f; }
  const half8v bones = {(_Float16)1.f, (_Float16)1.f, (_Float16)1.f, (_Float16)1.f,
                        (_Float16)1.f, (_Float16)1.f, (_Float16)1.f, (_Float16)1.f};

  // ---- VT register prefetch: FOUR NAMED uint4 scalars ----
  const uint4* vsrc = (const uint4*)VT_g;
  uint4 pv0, pv1, pv2, pv3;
  const int vc  = t >> 4;            // 0..15; rows vc, vc+16, vc+32, vc+48
  const int vch = t & 15;
  const int vswz = (vch * 8) ^ ((vc & 7) * 8);   // (vc+16k)&7 == vc&7

  // per-lane mask row base: rows i0 + rbase + mt*16 + m  (L2-hot)
  const unsigned char* mrow = maskb + (size_t)(i0 + rbase + m) * NDIM + quad * 8;
  uint2 mkA[4][4], mkB[4][4];   // double-buffered; static indexing (full unroll)

#define PREFETCH_V(js_)                                                        \
  { pv0 = vsrc[(size_t)(bt * 64 + vc     ) * 64 + (js_) * 16 + vch];           \
    pv1 = vsrc[(size_t)(bt * 64 + vc + 16) * 64 + (js_) * 16 + vch];           \
    pv2 = vsrc[(size_t)(bt * 64 + vc + 32) * 64 + (js_) * 16 + vch];           \
    pv3 = vsrc[(size_t)(bt * 64 + vc + 48) * 64 + (js_) * 16 + vch]; }

#define PREFETCH_M(mk_, js_)                                                   \
  { _Pragma("unroll")                                                          \
    for (int mt = 0; mt < 4; ++mt) {                                           \
      const unsigned char* mbp = mrow + (size_t)(mt * 16) * NDIM + (js_) * 128;\
      _Pragma("unroll")                                                        \
      for (int ksl = 0; ksl < 4; ++ksl)                                        \
        mk_[mt][ksl] = *(const uint2*)(mbp + ksl * 32);                        \
    } }

#define SLICE(mk_, js_, ksl_)                                                  \
  {                                                                            \
    const int jq = (ksl_) * 32 + quad * 8;                                     \
    half8v F8 = *(const half8v*)&sm.sF16[h][(js_) * 128 + jq];                 \
    half8v P8 = *(const half8v*)&sm.sP16[h][(js_) * 128 + jq];                 \
    const int vbase = (h * 32 + m) * 128 + (jq ^ ((m & 7) * 8));               \
    half8v b0 = *(const half8v*)&sm.u.s.vt[0][vbase];                          \
    half8v b1 = *(const half8v*)&sm.u.s.vt[0][vbase + 16 * 128];               \
    uint4 fu = __builtin_bit_cast(uint4, F8);                                  \
    uint4 pu = __builtin_bit_cast(uint4, P8);                                  \
    half2v f2a = __builtin_bit_cast(half2v, fu.x), f2b = __builtin_bit_cast(half2v, fu.y); \
    half2v f2c = __builtin_bit_cast(half2v, fu.z), f2d = __builtin_bit_cast(half2v, fu.w); \
    half2v p2a = __builtin_bit_cast(half2v, pu.x), p2b = __builtin_bit_cast(half2v, pu.y); \
    half2v p2c = __builtin_bit_cast(half2v, pu.z), p2d = __builtin_bit_cast(half2v, pu.w); \
    _Pragma("unroll")                                                          \
    for (int mt = 0; mt < 4; ++mt) {                                           \
      unsigned mw0 = mk_[mt][ksl_].x, mw1 = mk_[mt][ksl_].y;                   \
      uint4 eu;                                                                \
      eu.x = __builtin_bit_cast(unsigned,                                      \
               __builtin_elementwise_max(e2[mt] * f2a, q2[mt] * p2a)) &        \
             __builtin_amdgcn_perm(0u, mw0, 0x01010000u);                      \
      eu.y = __builtin_bit_cast(unsigned,                                      \
               __builtin_elementwise_max(e2[mt] * f2b, q2[mt] * p2b)) &        \
             __builtin_amdgcn_perm(0u, mw0, 0x03030202u);                      \
      eu.z = __builtin_bit_cast(unsigned,                                      \
               __builtin_elementwise_max(e2[mt] * f2c, q2[mt] * p2c)) &        \
             __builtin_amdgcn_perm(0u, mw1, 0x01010000u);                      \
      eu.w = __builtin_bit_cast(unsigned,                                      \
               __builtin_elementwise_max(e2[mt] * f2d, q2[mt] * p2d)) &        \
             __builtin_amdgcn_perm(0u, mw1, 0x03030202u);                      \
      half8v af = __builtin_bit_cast(half8v, eu);                              \
      acc[mt][0] = __builtin_amdgcn_mfma_f32_16x16x32_f16(af, b0,    acc[mt][0], 0, 0, 0); \
      acc[mt][1] = __builtin_amdgcn_mfma_f32_16x16x32_f16(af, b1,    acc[mt][1], 0, 0, 0); \
      accs[mt]   = __builtin_amdgcn_mfma_f32_16x16x32_f16(af, bones, accs[mt],   0, 0, 0); \
    }                                                                          \
  }

  // prologue: VT quarter 0 + masks for js=0 (issued before any barrier)
  PREFETCH_V(0);
  PREFETCH_M(mkA, 0);

#define QUARTER(mkX_, mkY_, js_)                                               \
  {                                                                            \
    __syncthreads();   /* prev quarter fully consumed */                       \
    *(uint4*)&sm.u.s.vt[vc     ][vswz] = pv0;                                  \
    *(uint4*)&sm.u.s.vt[vc + 16][vswz] = pv1;                                  \
    *(uint4*)&sm.u.s.vt[vc + 32][vswz] = pv2;                                  \
    *(uint4*)&sm.u.s.vt[vc + 48][vswz] = pv3;                                  \
    __syncthreads();                                                           \
    if ((js_) < 3) PREFETCH_V((js_) + 1);                                      \
    SLICE(mkX_, js_, 0);                                                       \
    SLICE(mkX_, js_, 1);                                                       \
    if ((js_) < 3) PREFETCH_M(mkY_, (js_) + 1);                                \
    SLICE(mkX_, js_, 2);                                                       \
    SLICE(mkX_, js_, 3);                                                       \
  }

  QUARTER(mkA, mkB, 0);
  QUARTER(mkB, mkA, 1);
  QUARTER(mkA, mkB, 2);
  QUARTER(mkB, mkA, 3);
#undef QUARTER
#undef SLICE
#undef PREFETCH_M
#undef PREFETCH_V

  __syncthreads();   // vt dead -> otile overlay
  // normalize by row sums (same C-layout row as acc -> no shuffle needed)
#pragma unroll
  for (int mt = 0; mt < 4; ++mt)
#pragma unroll
    for (int r = 0; r < 4; ++r) {
      float sc = __builtin_amdgcn_rcpf(accs[mt][r]);
      int i_loc = rbase + mt * 16 + quad * 4 + r;
#pragma unroll
      for (int nt = 0; nt < 2; ++nt)
        sm.u.e.otile[i_loc][h * 32 + nt * 16 + m] = acc[mt][nt][r] * sc;
    }
  __syncthreads();

  // LayerNorm over C=64 per row (128 rows, 2 threads/row x 32 ch)
  {
    int i = t & 127, cg = t >> 7;
    float s1 = 0.f, s2 = 0.f;
#pragma unroll
    for (int cc = 0; cc < 32; ++cc) {
      float v = sm.u.e.otile[i][cg * 32 + cc];
      s1 += v; s2 += v * v;
    }
    sm.u.e.rsum[cg][i] = s1;
    sm.u.e.rsq[cg][i]  = s2;
  }
  __syncthreads();
  if (t < 128) {
    int i = t;
    float s1 = sm.u.e.rsum[0][i] + sm.u.e.rsum[1][i];
    float s2 = sm.u.e.rsq[0][i]  + sm.u.e.rsq[1][i];
    float mu  = s1 * (1.f / 64.f);
    float var = s2 * (1.f / 64.f) - mu * mu;
    sm.u.e.mu[i] = mu;
    sm.u.e.rs[i] = rsqrtf(var + 1e-5f);
  }
  __syncthreads();
  {
    int i = t & 127, cg = t >> 7;
    float mu = sm.u.e.mu[i], rs = sm.u.e.rs[i];
    int n = i0 + i;
#pragma unroll
    for (int cc = 0; cc < 32; ++cc) {
      int c = cg * 32 + cc;
      float v = (sm.u.e.otile[i][c] - mu) * rs * gamma[c] + beta[c];
      out[((size_t)(b * CDIM + c) * TDIM + tt) * NDIM + n] = v;
    }
  }
}

// ---------------------------------------------------------------------------
extern "C" void kernel_launch(void* const* d_in, const int* in_sizes, int n_in,
                              void* d_out, int out_size, void* d_ws, size_t ws_size,
                              hipStream_t stream) {
  const float* x     = (const float*)d_in[0];
  const int*   gso   = (const int*)d_in[1];
  const float* Wq    = (const float*)d_in[2];
  const float* Wk    = (const float*)d_in[3];
  const float* Wv    = (const float*)d_in[4];
  const float* a_src = (const float*)d_in[5];
  const float* a_dst = (const float*)d_in[6];
  const float* gamma = (const float*)d_in[7];
  const float* beta  = (const float*)d_in[8];
  float* out = (float*)d_out;

  char* ws = (char*)d_ws;
  _Float16* VT_g  = (_Float16*)ws;
  float*    s_src = (float*)(ws + 12582912);
  float*    s_dst = (float*)(ws + 13369344);
  unsigned char* maskb = (unsigned char*)(ws + 14155776);

  k1_v<<<832, 256, 0, stream>>>(x, Wv, Wq, Wk, a_src, a_dst, gso,
                                VT_g, s_src, s_dst, maskb);
  k2_attn<<<768, 256, 0, stream>>>(VT_g, s_src, s_dst, maskb, gamma, beta, out);
}

// Round 9
// 122.516 us; speedup vs baseline: 1.0723x; 1.0335x over previous
//
#include <hip/hip_runtime.h>

#define CDIM 64
#define TDIM 24
#define NDIM 512
#define NBT  192   // B*T = 8*24

typedef float    float4v __attribute__((ext_vector_type(4)));
typedef _Float16 half8v  __attribute__((ext_vector_type(8)));
typedef _Float16 half4v  __attribute__((ext_vector_type(4)));
typedef _Float16 half2v  __attribute__((ext_vector_type(2)));

// ---------------------------------------------------------------------------
// Workspace layout (bytes):
//   VT_g   : _Float16 [NBT][4][1024][8]  0        (12582912 B)
//            FRAGMENT ORDER: [bt][js][h*8+ksl*2+b][lane] x 16B — k2's LDS
//            prefetch/commit/read are all lane-linear (bank-optimal).
//   s_src  : float    [NBT][2][512]    12582912   (786432 B)   (exp2 domain)
//   s_dst  : float    [NBT][2][512]    13369344   (786432 B)   (exp2 domain)
//   maskb  : u8       [512][512]       14155776   (262144 B)   {0x00,0xFF}
// Session budget: harness re-poison fills ~88-90 us/iter (immovable), k1
// ~1.5 us, k2 ~31-33 us. R8 PMC: k2 SQ_LDS_BANK_CONFLICT=4.13M — 21 extra
// cyc per vt ds_read_b128 (8-way: row stride 256B = 0 mod bank cycle; row
// bit 3 can't reach banks at 16B granularity). This round: VT_g reordered
// into MFMA-fragment order so all vt LDS traffic is wave_base + lane*16.
// ---------------------------------------------------------------------------

__device__ __forceinline__ float exp2_fast(float x) {
#if __has_builtin(__builtin_amdgcn_exp2f)
  return __builtin_amdgcn_exp2f(x);
#else
  return __expf(x * 0.69314718f);
#endif
}

// ======== kernel 1: V = X @ Wv^T (f16 MFMA) + score cols + mask pack ========
// 1D grid, 832 blocks:
//   blocks 0..767  : compute; qn = bx & 3 (node quarter = k2's js), bt = bx >> 2
//   blocks 768..831: gso -> byte-mask pack (pure BW, overlaps compute blocks)
struct SmemK1 {
  union {
    _Float16 xt[128][72];    // X tile [node][c], 144 B rows
    _Float16 vtb[64][136];   // V^T bounce [c][node]
  } big;                     // 18432 B
  _Float16 wv[64][72];       // Wv [d][k]             9216 B
  _Float16 wext[16][72];     // rows 0..3 = log2e * (a_h^T W_h), rest 0   2304 B
};                            // 29952 B

__launch_bounds__(256, 4)
__global__ void k1_v(const float* __restrict__ x,  const float* __restrict__ Wv,
                     const float* __restrict__ Wq, const float* __restrict__ Wk,
                     const float* __restrict__ a_src, const float* __restrict__ a_dst,
                     const int* __restrict__ gso,
                     _Float16* __restrict__ VT_g,
                     float* __restrict__ s_src_g, float* __restrict__ s_dst_g,
                     unsigned char* __restrict__ maskb) {
  const int t  = threadIdx.x;
  const int bx = blockIdx.x;

  if (bx >= 768) {   // ---- mask-pack blocks: 16 ints -> 16 mask bytes each ----
    int g = (bx - 768) * 256 + t;            // 0..16383
    const int4* gp = (const int4*)gso + (size_t)g * 4;
    unsigned w[4];
#pragma unroll
    for (int k = 0; k < 4; ++k) {
      int4 v = gp[k];
      w[k] = (v.x ? 0x000000FFu : 0u) | (v.y ? 0x0000FF00u : 0u) |
             (v.z ? 0x00FF0000u : 0u) | (v.w ? 0xFF000000u : 0u);
    }
    uint4 o; o.x = w[0]; o.y = w[1]; o.z = w[2]; o.w = w[3];
    ((uint4*)maskb)[g] = o;
    return;
  }

  __shared__ SmemK1 sm;
  const int qn = bx & 3;
  const int bt = bx >> 2;
  const int b  = bt / TDIM, tt = bt % TDIM;
  const int n0 = qn * 128;

  // stage Wv -> f16 LDS (dwordx4 loads)
#pragma unroll
  for (int it = 0; it < 4; ++it) {
    int idx = it * 256 + t;                 // 0..1023 float4s
    float4 vv = ((const float4*)Wv)[idx];
    int d = idx >> 4, k4 = (idx & 15) * 4;
    half4v h4; h4[0] = (_Float16)vv.x; h4[1] = (_Float16)vv.y;
    h4[2] = (_Float16)vv.z; h4[3] = (_Float16)vv.w;
    *(half4v*)&sm.wv[d][k4] = h4;
  }
  // wext: zero rows 4..15; rows 0..3 = log2e * (a_h^T W_h)  (exp2 domain)
  for (int z = t; z < 12 * 72; z += 256) ((_Float16*)sm.wext[4])[z] = (_Float16)0.f;
  if (t < 64) {
    int c = t;
    float s0 = 0.f, s1 = 0.f, d0 = 0.f, d1 = 0.f;
#pragma unroll
    for (int d = 0; d < 32; ++d) {
      s0 += a_src[d]      * Wq[d * 64 + c];
      s1 += a_src[32 + d] * Wq[(32 + d) * 64 + c];
      d0 += a_dst[d]      * Wk[d * 64 + c];
      d1 += a_dst[32 + d] * Wk[(32 + d) * 64 + c];
    }
    const float l2e = 1.44269504f;
    sm.wext[0][c] = (_Float16)(s0 * l2e); sm.wext[1][c] = (_Float16)(s1 * l2e);
    sm.wext[2][c] = (_Float16)(d0 * l2e); sm.wext[3][c] = (_Float16)(d1 * l2e);
  }
  // stage X tile (channel pairs -> half2)
  for (int it = 0; it < 16; ++it) {
    int idx = it * 256 + t;
    int cp = idx >> 7, n = idx & 127;
    int c0 = cp * 2;
    const float* base = x + ((size_t)(b * CDIM + c0) * TDIM + tt) * NDIM + n0 + n;
    half2v p; p[0] = (_Float16)base[0]; p[1] = (_Float16)base[(size_t)TDIM * NDIM];
    *(half2v*)&sm.big.xt[n][c0] = p;
  }
  __syncthreads();

  const int lane = t & 63, w = t >> 6;
  const int m = lane & 15, quad = lane >> 4;
  const int mbase = w * 32;   // 32 nodes per wave

  float4v acc[2][5];
#pragma unroll
  for (int mt = 0; mt < 2; ++mt)
#pragma unroll
    for (int nt = 0; nt < 5; ++nt)
#pragma unroll
      for (int r = 0; r < 4; ++r) acc[mt][nt][r] = 0.f;

#pragma unroll
  for (int ks = 0; ks < 2; ++ks) {
    half8v af[2], bf[5];
#pragma unroll
    for (int mt = 0; mt < 2; ++mt)
      af[mt] = *(const half8v*)&sm.big.xt[mbase + mt * 16 + m][ks * 32 + quad * 8];
#pragma unroll
    for (int nt = 0; nt < 4; ++nt)
      bf[nt] = *(const half8v*)&sm.wv[nt * 16 + m][ks * 32 + quad * 8];
    bf[4] = *(const half8v*)&sm.wext[m][ks * 32 + quad * 8];
#pragma unroll
    for (int mt = 0; mt < 2; ++mt)
#pragma unroll
      for (int nt = 0; nt < 5; ++nt)
        acc[mt][nt] = __builtin_amdgcn_mfma_f32_16x16x32_f16(af[mt], bf[nt], acc[mt][nt], 0, 0, 0);
  }

  // scatter score columns (col 0/1 = ssrc h0/h1, col 2/3 = sdst h0/h1)
  if (m < 4) {
    float* basep = (m < 2 ? s_src_g : s_dst_g) + (size_t)(bt * 2 + (m & 1)) * NDIM;
#pragma unroll
    for (int mt = 0; mt < 2; ++mt)
#pragma unroll
      for (int r = 0; r < 4; ++r)
        basep[n0 + mbase + mt * 16 + quad * 4 + r] = acc[mt][4][r];
  }
  __syncthreads();   // xt fully consumed before overlay

  // V^T bounce into LDS (pack node pairs)
#pragma unroll
  for (int mt = 0; mt < 2; ++mt)
#pragma unroll
    for (int nt = 0; nt < 4; ++nt)
#pragma unroll
      for (int r = 0; r < 4; r += 2) {
        int nl = mbase + mt * 16 + quad * 4 + r;
        int c  = nt * 16 + m;
        half2v p = __builtin_bit_cast(half2v,
            __builtin_amdgcn_cvt_pkrtz(acc[mt][nt][r], acc[mt][nt][r + 1]));
        *(half2v*)&sm.big.vtb[c][nl] = p;
      }
  __syncthreads();

  // fragment-ordered V^T -> global (coalesced 16B/thread x 4):
  // frag f = (fh, fksl, fb, flane): c = fh*32 + fb*16 + (flane&15),
  // jq = fksl*32 + (flane>>4)*8 (halfs within this 128-node quarter)
  const _Float16* vtbf = (const _Float16*)sm.big.vtb;   // row stride 136 halfs
#pragma unroll
  for (int it = 0; it < 4; ++it) {
    int f    = it * 256 + t;            // 0..1023
    int fh   = f >> 9;
    int fksl = (f >> 7) & 3;
    int fb   = (f >> 6) & 1;
    int fl   = f & 63;
    int c  = fh * 32 + fb * 16 + (fl & 15);
    int jq = fksl * 32 + (fl >> 4) * 8;
    uint4 v = *(const uint4*)(vtbf + c * 136 + jq);
    ((uint4*)VT_g)[((size_t)bt * 4 + qn) * 1024 + f] = v;
  }
}

// ======== kernel 2: masked softmax(P) @ V + LayerNorm + transpose ===========
// ROWBLK=128: 4 i-tiles x 192 bt = 768 blocks (3/CU). XCD swizzle keeps the
// 4 blocks sharing one 64 KB VT panel on one XCD's L2:
//   id = (bt&7) + 8*itile + 32*(bt>>3)
// e_ij = max(E_i*F_j, Q_i*P_j), packed-f16 half2 ops. Masks direct from
// global (L2-hot). VT is in FRAGMENT ORDER: per js quarter, 1024 x 16B slots
// [h*8+ksl*2+b][lane] -> prefetch (global, linear), commit (LDS write,
// wave_base+lane*16) and slice reads (same) are all bank-optimal; no XOR
// swizzle needed. Schedule = R4's measured-best 2-barrier-per-quarter.
struct SmemK2 {
  union {
    _Float16 vt[8192];                                               // 16384
    struct { float otile[128][66]; float rsum[2][128]; float rsq[2][128];
             float mu[128]; float rs[128]; } e;                      // 36864
  } u;
  _Float16 sF16[2][512];   // 2048  F_j  = 2^{d'_j}   (f16)
  _Float16 sP16[2][512];   // 2048  Fp_j = 2^{0.2 d'_j} (f16)
};                          // 40960 B

__launch_bounds__(256, 3)
__global__ void k2_attn(const _Float16* __restrict__ VT_g,
                        const float* __restrict__ s_src_g, const float* __restrict__ s_dst_g,
                        const unsigned char* __restrict__ maskb,
                        const float* __restrict__ gamma, const float* __restrict__ beta,
                        float* __restrict__ out) {
  __shared__ SmemK2 sm;
  const int t     = threadIdx.x;
  const int id    = blockIdx.x;
  const int itile = (id >> 3) & 3;
  const int bt    = ((id >> 5) << 3) | (id & 7);
  const int i0    = itile * 128;
  const int b     = bt / TDIM, tt = bt % TDIM;
  const int lane  = t & 63, w = t >> 6;
  const int h = w >> 1, ihalf = w & 1;
  const int m = lane & 15, quad = lane >> 4;
  const int rbase = ihalf * 64;    // this wave's 64-row half of the 128-row tile

  // stage F/Fp as f16 (1024 exp2 pairs per block)
  for (int it = 0; it < 4; ++it) {
    int idx = it * 256 + t;
    float d = s_dst_g[(size_t)bt * 2 * NDIM + idx];
    ((_Float16*)sm.sF16)[idx] = (_Float16)exp2_fast(d);
    ((_Float16*)sm.sP16)[idx] = (_Float16)exp2_fast(0.2f * d);
  }
  // per-row source factors as packed half2 (bias -6 keeps products f16-normal)
  half2v e2[4], q2[4];
#pragma unroll
  for (int mt = 0; mt < 4; ++mt) {
    float sv = s_src_g[(size_t)(bt * 2 + h) * NDIM + i0 + rbase + mt * 16 + m];
    _Float16 ev = (_Float16)exp2_fast(sv - 6.f);
    _Float16 qv = (_Float16)exp2_fast(0.2f * sv - 6.f);
    e2[mt][0] = ev; e2[mt][1] = ev;
    q2[mt][0] = qv; q2[mt][1] = qv;
  }

  float4v acc[4][2], accs[4];
#pragma unroll
  for (int mt = 0; mt < 4; ++mt)
#pragma unroll
    for (int r = 0; r < 4; ++r) { acc[mt][0][r] = 0.f; acc[mt][1][r] = 0.f; accs[mt][r] = 0.f; }
  const half8v bones = {(_Float16)1.f, (_Float16)1.f, (_Float16)1.f, (_Float16)1.f,
                        (_Float16)1.f, (_Float16)1.f, (_Float16)1.f, (_Float16)1.f};

  // ---- VT register prefetch: FOUR NAMED uint4 scalars (linear slots) ----
  const uint4* vsrc = (const uint4*)VT_g;
  uint4 pv0, pv1, pv2, pv3;

  // per-lane mask row base: rows i0 + rbase + mt*16 + m  (L2-hot)
  const unsigned char* mrow = maskb + (size_t)(i0 + rbase + m) * NDIM + quad * 8;

#define PREFETCH_V(js_)                                                        \
  { size_t vb = ((size_t)bt * 4 + (js_)) * 1024 + t;                           \
    pv0 = vsrc[vb];       pv1 = vsrc[vb + 256];                                \
    pv2 = vsrc[vb + 512]; pv3 = vsrc[vb + 768]; }

#define SLICE(js_, ksl_)                                                       \
  {                                                                            \
    const int jq = (ksl_) * 32 + quad * 8;                                     \
    half8v F8 = *(const half8v*)&sm.sF16[h][(js_) * 128 + jq];                 \
    half8v P8 = *(const half8v*)&sm.sP16[h][(js_) * 128 + jq];                 \
    const int fs = ((h * 8 + (ksl_) * 2) * 64 + lane) * 8;                     \
    half8v b0 = *(const half8v*)&sm.u.vt[fs];                                  \
    half8v b1 = *(const half8v*)&sm.u.vt[fs + 512];                            \
    uint4 fu = __builtin_bit_cast(uint4, F8);                                  \
    uint4 pu = __builtin_bit_cast(uint4, P8);                                  \
    half2v f2a = __builtin_bit_cast(half2v, fu.x), f2b = __builtin_bit_cast(half2v, fu.y); \
    half2v f2c = __builtin_bit_cast(half2v, fu.z), f2d = __builtin_bit_cast(half2v, fu.w); \
    half2v p2a = __builtin_bit_cast(half2v, pu.x), p2b = __builtin_bit_cast(half2v, pu.y); \
    half2v p2c = __builtin_bit_cast(half2v, pu.z), p2d = __builtin_bit_cast(half2v, pu.w); \
    _Pragma("unroll")                                                          \
    for (int mt = 0; mt < 4; ++mt) {                                           \
      unsigned mw0 = mk[mt][ksl_].x, mw1 = mk[mt][ksl_].y;                     \
      uint4 eu;                                                                \
      eu.x = __builtin_bit_cast(unsigned,                                      \
               __builtin_elementwise_max(e2[mt] * f2a, q2[mt] * p2a)) &        \
             __builtin_amdgcn_perm(0u, mw0, 0x01010000u);                      \
      eu.y = __builtin_bit_cast(unsigned,                                      \
               __builtin_elementwise_max(e2[mt] * f2b, q2[mt] * p2b)) &        \
             __builtin_amdgcn_perm(0u, mw0, 0x03030202u);                      \
      eu.z = __builtin_bit_cast(unsigned,                                      \
               __builtin_elementwise_max(e2[mt] * f2c, q2[mt] * p2c)) &        \
             __builtin_amdgcn_perm(0u, mw1, 0x01010000u);                      \
      eu.w = __builtin_bit_cast(unsigned,                                      \
               __builtin_elementwise_max(e2[mt] * f2d, q2[mt] * p2d)) &        \
             __builtin_amdgcn_perm(0u, mw1, 0x03030202u);                      \
      half8v af = __builtin_bit_cast(half8v, eu);                              \
      acc[mt][0] = __builtin_amdgcn_mfma_f32_16x16x32_f16(af, b0,    acc[mt][0], 0, 0, 0); \
      acc[mt][1] = __builtin_amdgcn_mfma_f32_16x16x32_f16(af, b1,    acc[mt][1], 0, 0, 0); \
      accs[mt]   = __builtin_amdgcn_mfma_f32_16x16x32_f16(af, bones, accs[mt],   0, 0, 0); \
    }                                                                          \
  }

  PREFETCH_V(0);

#pragma unroll
  for (int js = 0; js < 4; ++js) {
    __syncthreads();   // prev quarter fully consumed
    // commit prefetched VT quarter to LDS (lane-linear 16B slots)
    ((uint4*)sm.u.vt)[t      ] = pv0;
    ((uint4*)sm.u.vt)[t + 256] = pv1;
    ((uint4*)sm.u.vt)[t + 512] = pv2;
    ((uint4*)sm.u.vt)[t + 768] = pv3;
    __syncthreads();
    if (js < 3) PREFETCH_V(js + 1);   // latency hides under this quarter's compute

    // mask bytes for this quarter: 16 x uint2 per lane
    uint2 mk[4][4];
#pragma unroll
    for (int mt = 0; mt < 4; ++mt) {
      const unsigned char* mbp = mrow + (size_t)(mt * 16) * NDIM + js * 128;
#pragma unroll
      for (int ksl = 0; ksl < 4; ++ksl)
        mk[mt][ksl] = *(const uint2*)(mbp + ksl * 32);
    }

    SLICE(js, 0);
    SLICE(js, 1);
    SLICE(js, 2);
    SLICE(js, 3);
  }
#undef SLICE
#undef PREFETCH_V

  __syncthreads();   // vt dead -> otile overlay
  // normalize by row sums (same C-layout row as acc -> no shuffle needed)
#pragma unroll
  for (int mt = 0; mt < 4; ++mt)
#pragma unroll
    for (int r = 0; r < 4; ++r) {
      float sc = __builtin_amdgcn_rcpf(accs[mt][r]);
      int i_loc = rbase + mt * 16 + quad * 4 + r;
#pragma unroll
      for (int nt = 0; nt < 2; ++nt)
        sm.u.e.otile[i_loc][h * 32 + nt * 16 + m] = acc[mt][nt][r] * sc;
    }
  __syncthreads();

  // LayerNorm over C=64 per row (128 rows, 2 threads/row x 32 ch)
  {
    int i = t & 127, cg = t >> 7;
    float s1 = 0.f, s2 = 0.f;
#pragma unroll
    for (int cc = 0; cc < 32; ++cc) {
      float v = sm.u.e.otile[i][cg * 32 + cc];
      s1 += v; s2 += v * v;
    }
    sm.u.e.rsum[cg][i] = s1;
    sm.u.e.rsq[cg][i]  = s2;
  }
  __syncthreads();
  if (t < 128) {
    int i = t;
    float s1 = sm.u.e.rsum[0][i] + sm.u.e.rsum[1][i];
    float s2 = sm.u.e.rsq[0][i]  + sm.u.e.rsq[1][i];
    float mu  = s1 * (1.f / 64.f);
    float var = s2 * (1.f / 64.f) - mu * mu;
    sm.u.e.mu[i] = mu;
    sm.u.e.rs[i] = rsqrtf(var + 1e-5f);
  }
  __syncthreads();
  {
    int i = t & 127, cg = t >> 7;
    float mu = sm.u.e.mu[i], rs = sm.u.e.rs[i];
    int n = i0 + i;
#pragma unroll
    for (int cc = 0; cc < 32; ++cc) {
      int c = cg * 32 + cc;
      float v = (sm.u.e.otile[i][c] - mu) * rs * gamma[c] + beta[c];
      out[((size_t)(b * CDIM + c) * TDIM + tt) * NDIM + n] = v;
    }
  }
}

// ---------------------------------------------------------------------------
extern "C" void kernel_launch(void* const* d_in, const int* in_sizes, int n_in,
                              void* d_out, int out_size, void* d_ws, size_t ws_size,
                              hipStream_t stream) {
  const float* x     = (const float*)d_in[0];
  const int*   gso   = (const int*)d_in[1];
  const float* Wq    = (const float*)d_in[2];
  const float* Wk    = (const float*)d_in[3];
  const float* Wv    = (const float*)d_in[4];
  const float* a_src = (const float*)d_in[5];
  const float* a_dst = (const float*)d_in[6];
  const float* gamma = (const float*)d_in[7];
  const float* beta  = (const float*)d_in[8];
  float* out = (float*)d_out;

  char* ws = (char*)d_ws;
  _Float16* VT_g  = (_Float16*)ws;
  float*    s_src = (float*)(ws + 12582912);
  float*    s_dst = (float*)(ws + 13369344);
  unsigned char* maskb = (unsigned char*)(ws + 14155776);

  k1_v<<<832, 256, 0, stream>>>(x, Wv, Wq, Wk, a_src, a_dst, gso,
                                VT_g, s_src, s_dst, maskb);
  k2_attn<<<768, 256, 0, stream>>>(VT_g, s_src, s_dst, maskb, gamma, beta, out);
}